// Round 10
// baseline (444.413 us; speedup 1.0000x reference)
//
#include <hip/hip_runtime.h>
#include <hip/hip_bf16.h>

#define B_   64
#define S_   2048
#define TRG_ 512
#define K_   1024

typedef short short8 __attribute__((ext_vector_type(8)));
typedef short short4v __attribute__((ext_vector_type(4)));
typedef float f32x4  __attribute__((ext_vector_type(4)));
typedef unsigned short us4 __attribute__((ext_vector_type(4)));

__device__ __forceinline__ unsigned short f2bf(float f) {
    union { float f; unsigned int u; } v; v.f = f;
    unsigned int u = v.u;
    unsigned int r = (u + 0x7fffu + ((u >> 16) & 1u)) >> 16;  // RNE
    return (unsigned short)r;
}

__device__ __forceinline__ short4v cvt4(f32x4 a) {
    union { __hip_bfloat162 h[2]; short4v v; } u;
    u.h[0] = __float22bfloat162_rn(float2{a[0], a[1]});
    u.h[1] = __float22bfloat162_rn(float2{a[2], a[3]});
    return u.v;
}

// ---------------- W_en fp32 -> bf16 ----------------
__global__ void wen_convert_kernel(const float* __restrict__ Wen,
                                   unsigned short* __restrict__ Wbf) {
    int idx = blockIdx.x * 256 + threadIdx.x;
    float4 f = ((const float4*)Wen)[idx];
    us4 o = { f2bf(f.x), f2bf(f.y), f2bf(f.z), f2bf(f.w) };
    ((us4*)Wbf)[idx] = o;
}

// ---------------- deproj ----------------
__global__ void deproj_kernel(const float* __restrict__ dehy,
                              const float* __restrict__ Wde,
                              const float* __restrict__ ben,
                              float* __restrict__ dp) {
    int b = blockIdx.x >> 1;
    int h = ((blockIdx.x & 1) << 8) + threadIdx.x;
    const float4* dv = (const float4*)(dehy + (size_t)b * TRG_);
    const float4* wv = (const float4*)(Wde + (size_t)h * TRG_);
    float s = ben[h];
    #pragma unroll 4
    for (int t = 0; t < TRG_ / 4; ++t) {
        float4 a = dv[t], w = wv[t];
        s += a.x * w.x + a.y * w.y + a.z * w.z + a.w * w.w;
    }
    dp[b * TRG_ + h] = s;
}

// ---------------- fused score GEMM + tanh + w_warp reduce + mask ----------------
// R9 structure, ONE change: B is register-double-buffered per wave (prefetch
// distance 1 from L2), NO B-LDS relay, NO global_load_lds -> the per-step
// __syncthreads drains only lgkmcnt (A ds_write); global loads ride across
// barriers in VGPRs. LDS = A dbuf 8 KB + red 2 KB.
__global__ __launch_bounds__(512, 4) void score_kernel(
    const float* __restrict__ enhy,
    const unsigned short* __restrict__ Wbf,
    const float* __restrict__ dp,
    const float* __restrict__ past_attn,
    const int* __restrict__ src_mask,
    const float* __restrict__ w_cv,
    const float* __restrict__ w_warp,
    float* __restrict__ out_ee)
{
    __shared__ unsigned short Abuf[2][64 * 32];    // 8 KB
    __shared__ float red[8][64];                   // 2 KB

    const int tid  = threadIdx.x;
    const int lane = tid & 63;
    const int w    = tid >> 6;       // 0..7 (n-slice)
    const int lj   = lane & 15;
    const int lg   = lane >> 4;
    const int m0   = blockIdx.x * 64;    // flat row into [B*S]
    const int b    = m0 >> 11;

    const int kx = ((lg ^ ((lj >> 1) & 3)) << 4);

    f32x4 acc[4][4];
    const f32x4 fz = {0.f, 0.f, 0.f, 0.f};
    #pragma unroll
    for (int i = 0; i < 4; ++i)
        #pragma unroll
        for (int j = 0; j < 4; ++j) acc[i][j] = fz;

    // A staging: thread -> (row = tid>>3, 4-float group kq = tid&7); swizzled dest
    const int arow = tid >> 3;
    const int akq  = tid & 7;
    const float* aSrc = enhy + (size_t)(m0 + arow) * K_ + (akq << 2);
    const int aDstByte = arow * 64 + (((akq >> 1) ^ ((arow >> 1) & 3)) << 4) + ((akq & 1) << 3);

    // B direct fragment base: wave w owns cols w*64..+64; frag fn at row (w<<6)+(fn<<4)+lj
    const unsigned short* bRow = Wbf + (size_t)((w << 6) + lj) * K_ + (lg << 3);

#define LOADA(R, kt) { R = __builtin_nontemporal_load((const f32x4*)(aSrc + ((kt) << 5))); }
#define WRITEA(sel, R) { \
    *(short4v*)((char*)&Abuf[0][0] + (sel) * 4096 + aDstByte) = cvt4(R); }
#define LOADB(B0, B1, B2, B3, kt) { const int ko_ = (kt) << 5; \
    B0 = *(const short8*)(bRow + (size_t)(0 * 16) * K_ + ko_); \
    B1 = *(const short8*)(bRow + (size_t)(1 * 16) * K_ + ko_); \
    B2 = *(const short8*)(bRow + (size_t)(2 * 16) * K_ + ko_); \
    B3 = *(const short8*)(bRow + (size_t)(3 * 16) * K_ + ko_); }
#define COMPUTE(sel, B0, B1, B2, B3) { \
    const char* Abase = (const char*)&Abuf[0][0] + (sel) * 4096; \
    _Pragma("unroll") \
    for (int fm = 0; fm < 4; ++fm) { \
        short8 af = *(const short8*)(Abase + ((fm << 4) + lj) * 64 + kx); \
        acc[fm][0] = __builtin_amdgcn_mfma_f32_16x16x32_bf16(af, B0, acc[fm][0], 0, 0, 0); \
        acc[fm][1] = __builtin_amdgcn_mfma_f32_16x16x32_bf16(af, B1, acc[fm][1], 0, 0, 0); \
        acc[fm][2] = __builtin_amdgcn_mfma_f32_16x16x32_bf16(af, B2, acc[fm][2], 0, 0, 0); \
        acc[fm][3] = __builtin_amdgcn_mfma_f32_16x16x32_bf16(af, B3, acc[fm][3], 0, 0, 0); \
    } }

// One K-step. BC*=current B regs, BN*=prefetch target, AW=A(kt+1) regs to write,
// AL=reg to fill with A(kt+2). DOB/DOA/DOW are 0/1 literals.
#define STEP(kt, BC0,BC1,BC2,BC3, BN0,BN1,BN2,BN3, AW, AL, DOB, DOA, DOW) { \
    if (DOB) LOADB(BN0, BN1, BN2, BN3, (kt) + 1) \
    if (DOA) LOADA(AL, (kt) + 2) \
    COMPUTE((kt) & 1, BC0, BC1, BC2, BC3) \
    if (DOW) WRITEA(((kt) & 1) ^ 1, AW) \
    __syncthreads(); \
}

    short8 bA0, bA1, bA2, bA3, bB0, bB1, bB2, bB3;
    f32x4 a_c, a_n;

    // ---- prologue: A(0) staged; B(0) in regs; A(1) in regs ----
    LOADA(a_c, 0);
    LOADB(bA0, bA1, bA2, bA3, 0)
    WRITEA(0, a_c);                 // waits A(0) load
    LOADA(a_n, 1);
    __syncthreads();

    // ---- main loop: even kt uses bA set, odd uses bB ----
    for (int kt2 = 0; kt2 < 30; kt2 += 2) {
        STEP(kt2,     bA0,bA1,bA2,bA3, bB0,bB1,bB2,bB3, a_n, a_c, 1, 1, 1)
        STEP(kt2 + 1, bB0,bB1,bB2,bB3, bA0,bA1,bA2,bA3, a_c, a_n, 1, 1, 1)
    }
    STEP(30, bA0,bA1,bA2,bA3, bB0,bB1,bB2,bB3, a_n, a_c, 1, 0, 1)   // prefetch B(31); write A(31)
    STEP(31, bB0,bB1,bB2,bB3, bA0,bA1,bA2,bA3, a_c, a_n, 0, 0, 0)   // final compute

#undef LOADA
#undef WRITEA
#undef LOADB
#undef COMPUTE
#undef STEP

    // ---- epilogue: v = acc + dep + pa*wcv; tanh; *w_warp; reduce over h ----
    float dep4[4], wcv4[4], wwp4[4];
    #pragma unroll
    for (int fn = 0; fn < 4; ++fn) {
        int h = (w << 6) + (fn << 4) + lj;
        dep4[fn] = dp[b * TRG_ + h];
        wcv4[fn] = w_cv[h];
        wwp4[fn] = w_warp[h];
    }
    #pragma unroll
    for (int fm = 0; fm < 4; ++fm) {
        #pragma unroll
        for (int reg = 0; reg < 4; ++reg) {
            int row = (fm << 4) + (lg << 2) + reg;       // 0..63
            float pa = past_attn[m0 + row];
            float p = 0.f;
            #pragma unroll
            for (int fn = 0; fn < 4; ++fn) {
                float v = acc[fm][fn][reg] + dep4[fn] + pa * wcv4[fn];
                float e = __expf(2.f * v);                       // tanh = 1 - 2/(e^{2v}+1)
                float t = 1.f - 2.f * __builtin_amdgcn_rcpf(e + 1.f);
                p += t * wwp4[fn];
            }
            p += __shfl_xor(p, 1);
            p += __shfl_xor(p, 2);
            p += __shfl_xor(p, 4);
            p += __shfl_xor(p, 8);
            if (lj == 0) red[w][row] = p;
        }
    }
    __syncthreads();
    if (tid < 64) {
        float ee = 0.f;
        #pragma unroll
        for (int ww = 0; ww < 8; ++ww) ee += red[ww][tid];
        int msk = src_mask[m0 + tid];
        if (msk == 0) ee = -1e20f;
        out_ee[m0 + tid] = ee;
    }
}

// ---------------- softmax over S per batch row ----------------
__global__ void softmax_kernel(const float* __restrict__ ee, float* __restrict__ attn) {
    int b = blockIdx.x, tid = threadIdx.x;
    const float* row = ee + (size_t)b * S_;
    float v[8]; float mx = -3.0e38f;
    #pragma unroll
    for (int i = 0; i < 8; ++i) { v[i] = row[tid + (i << 8)]; mx = fmaxf(mx, v[i]); }
    #pragma unroll
    for (int off = 32; off > 0; off >>= 1) mx = fmaxf(mx, __shfl_xor(mx, off));
    __shared__ float sred[4];
    int w = tid >> 6, lane = tid & 63;
    if (lane == 0) sred[w] = mx;
    __syncthreads();
    mx = fmaxf(fmaxf(sred[0], sred[1]), fmaxf(sred[2], sred[3]));
    float sum = 0.f;
    #pragma unroll
    for (int i = 0; i < 8; ++i) { v[i] = __expf(v[i] - mx); sum += v[i]; }
    #pragma unroll
    for (int off = 32; off > 0; off >>= 1) sum += __shfl_xor(sum, off);
    __syncthreads();
    if (lane == 0) sred[w] = sum;
    __syncthreads();
    sum = sred[0] + sred[1] + sred[2] + sred[3];
    float inv = 1.f / sum;
    float* orow = attn + (size_t)b * S_;
    #pragma unroll
    for (int i = 0; i < 8; ++i) orow[tid + (i << 8)] = v[i] * inv;
}

// ---------------- context ----------------
__global__ void ctx_partial_kernel(const float* __restrict__ attn,
                                   const float* __restrict__ enhy,
                                   float* __restrict__ part) {
    int bx = blockIdx.x;
    int b = bx >> 5, sc = bx & 31;
    int tid = threadIdx.x;
    const float4* e4 = (const float4*)(enhy + ((size_t)b * S_ + sc * 64) * K_);
    const float* ar = attn + (size_t)b * S_ + sc * 64;
    float4 acc = {0.f, 0.f, 0.f, 0.f};
    #pragma unroll 8
    for (int s = 0; s < 64; ++s) {
        float a = ar[s];
        float4 ev = e4[(size_t)s * 256 + tid];
        acc.x += a * ev.x; acc.y += a * ev.y; acc.z += a * ev.z; acc.w += a * ev.w;
    }
    ((float4*)part)[(size_t)(sc * 64 + b) * 256 + tid] = acc;
}

__global__ void ctx_reduce_kernel(const float* __restrict__ part, float* __restrict__ outc) {
    int idx = blockIdx.x * 256 + threadIdx.x;
    int b = idx >> 10, d = idx & 1023;
    float s = 0.f;
    #pragma unroll
    for (int sc = 0; sc < 32; ++sc) s += part[(size_t)((sc << 6) + b) * 1024 + d];
    outc[idx] = s;
}

extern "C" void kernel_launch(void* const* d_in, const int* in_sizes, int n_in,
                              void* d_out, int out_size, void* d_ws, size_t ws_size,
                              hipStream_t stream) {
    (void)in_sizes; (void)n_in; (void)out_size; (void)ws_size;

    const float* dehy = (const float*)d_in[0];
    const float* enhy = (const float*)d_in[1];
    const float* past = (const float*)d_in[2];
    const int*   mask = (const int*)d_in[3];
    const float* Wen  = (const float*)d_in[4];
    const float* ben  = (const float*)d_in[5];
    const float* Wde  = (const float*)d_in[6];
    const float* wcv  = (const float*)d_in[7];
    const float* wwp  = (const float*)d_in[8];

    float* out      = (float*)d_out;
    float* out_c    = out;                      // 64*1024
    float* out_attn = out + 65536;              // 64*2048
    float* out_ee   = out + 65536 + 131072;     // 64*2048

    char* ws = (char*)d_ws;
    unsigned short* Wbf = (unsigned short*)ws;              // 1 MB
    float* dp   = (float*)(ws + (1 << 20));                 // 128 KB
    float* part = (float*)(ws + (1 << 20) + (1 << 17));     // 8 MB

    wen_convert_kernel<<<512, 256, 0, stream>>>(Wen, Wbf);
    deproj_kernel<<<128, 256, 0, stream>>>(dehy, Wde, ben, dp);
    score_kernel<<<2048, 512, 0, stream>>>(enhy, Wbf, dp, past, mask, wcv, wwp, out_ee);
    softmax_kernel<<<64, 256, 0, stream>>>(out_ee, out_attn);
    ctx_partial_kernel<<<2048, 256, 0, stream>>>(out_attn, enhy, part);
    ctx_reduce_kernel<<<256, 256, 0, stream>>>(part, out_c);
}

// Round 11
// 365.042 us; speedup vs baseline: 1.2174x; 1.2174x over previous
//
#include <hip/hip_runtime.h>
#include <hip/hip_bf16.h>

#define B_   64
#define S_   2048
#define TRG_ 512
#define K_   1024

typedef short short8 __attribute__((ext_vector_type(8)));
typedef short short4v __attribute__((ext_vector_type(4)));
typedef float f32x4  __attribute__((ext_vector_type(4)));
typedef unsigned short us4 __attribute__((ext_vector_type(4)));

__device__ __forceinline__ unsigned short f2bf(float f) {
    union { float f; unsigned int u; } v; v.f = f;
    unsigned int u = v.u;
    unsigned int r = (u + 0x7fffu + ((u >> 16) & 1u)) >> 16;  // RNE
    return (unsigned short)r;
}

__device__ __forceinline__ short4v cvt4(f32x4 a) {
    union { __hip_bfloat162 h[2]; short4v v; } u;
    u.h[0] = __float22bfloat162_rn(float2{a[0], a[1]});
    u.h[1] = __float22bfloat162_rn(float2{a[2], a[3]});
    return u.v;
}

// ---------------- W_en fp32 -> bf16 ----------------
__global__ void wen_convert_kernel(const float* __restrict__ Wen,
                                   unsigned short* __restrict__ Wbf) {
    int idx = blockIdx.x * 256 + threadIdx.x;
    float4 f = ((const float4*)Wen)[idx];
    us4 o = { f2bf(f.x), f2bf(f.y), f2bf(f.z), f2bf(f.w) };
    ((us4*)Wbf)[idx] = o;
}

// ---------------- deproj ----------------
__global__ void deproj_kernel(const float* __restrict__ dehy,
                              const float* __restrict__ Wde,
                              const float* __restrict__ ben,
                              float* __restrict__ dp) {
    int b = blockIdx.x >> 1;
    int h = ((blockIdx.x & 1) << 8) + threadIdx.x;
    const float4* dv = (const float4*)(dehy + (size_t)b * TRG_);
    const float4* wv = (const float4*)(Wde + (size_t)h * TRG_);
    float s = ben[h];
    #pragma unroll 4
    for (int t = 0; t < TRG_ / 4; ++t) {
        float4 a = dv[t], w = wv[t];
        s += a.x * w.x + a.y * w.y + a.z * w.z + a.w * w.w;
    }
    dp[b * TRG_ + h] = s;
}

// ---------------- fused score GEMM + tanh + w_warp reduce + mask ----------------
// R9 base, ONE structural change: B is SINGLE-buffered (32 KB) -> LDS 42 KB ->
// 3 blocks/CU (24 waves). Cross-block TLP (m114) covers the exposed B-latency.
// Barriers are raw+counted: mid-step vmcnt(1)+lgkm(0) (A nt-load for kt+2 keeps
// flying, distance-2, never drained); end-step lgkm(0) only.
__global__ __launch_bounds__(512, 4) void score_kernel(
    const float* __restrict__ enhy,
    const unsigned short* __restrict__ Wbf,
    const float* __restrict__ dp,
    const float* __restrict__ past_attn,
    const int* __restrict__ src_mask,
    const float* __restrict__ w_cv,
    const float* __restrict__ w_warp,
    float* __restrict__ out_ee)
{
    __shared__ unsigned short Bbuf[512 * 32];      // 32 KB (single buffer)
    __shared__ unsigned short Abuf[2][64 * 32];    // 8 KB
    __shared__ float red[8][64];                   // 2 KB

    const int tid  = threadIdx.x;
    const int lane = tid & 63;
    const int w    = tid >> 6;       // 0..7 (n-slice)
    const int lj   = lane & 15;
    const int lg   = lane >> 4;
    const int m0   = blockIdx.x * 64;    // flat row into [B*S]
    const int b    = m0 >> 11;

    const int kx = ((lg ^ ((lj >> 1) & 3)) << 4);

    f32x4 acc[4][4];
    const f32x4 fz = {0.f, 0.f, 0.f, 0.f};
    #pragma unroll
    for (int i = 0; i < 4; ++i)
        #pragma unroll
        for (int j = 0; j < 4; ++j) acc[i][j] = fz;

    // A staging: thread -> (row = tid>>3, 4-float group kq = tid&7); swizzled dest
    const int arow = tid >> 3;
    const int akq  = tid & 7;
    const float* aSrc = enhy + (size_t)(m0 + arow) * K_ + (akq << 2);
    const int aDstByte = arow * 64 + (((akq >> 1) ^ ((arow >> 1) & 3)) << 4) + ((akq & 1) << 3);

    // B staging: pre-swizzled source, linear LDS dest (wave-uniform + lane*16)
    const int brow0 = tid >> 2;
    const int bkc0  = tid & 3;
    const unsigned short* bSrc0 = Wbf + (size_t)brow0 * K_ + ((bkc0 ^ ((brow0 >> 1) & 3)) << 3);
    const int bDst0 = w * 1024;

#define LOADA(R, kt) { R = __builtin_nontemporal_load((const f32x4*)(aSrc + ((kt) << 5))); }
#define WRITEA(sel, R) { \
    *(short4v*)((char*)&Abuf[0][0] + (sel) * 4096 + aDstByte) = cvt4(R); }
#define STAGEB(kt) { \
    _Pragma("unroll") \
    for (int j_ = 0; j_ < 4; ++j_) { \
        __builtin_amdgcn_global_load_lds( \
            (const __attribute__((address_space(1))) void*)(bSrc0 + (size_t)j_ * 128 * K_ + ((kt) << 5)), \
            (__attribute__((address_space(3))) void*)((char*)&Bbuf[0] + bDst0 + j_ * 8192), \
            16, 0, 0); \
    } }
// mid-step barrier: wait the 4 B gload_lds (leave newest N vm ops flying) + A ds_write
#define MIDBAR(N) \
    asm volatile("s_waitcnt vmcnt(" #N ") lgkmcnt(0)" ::: "memory"); \
    __builtin_amdgcn_sched_barrier(0); \
    __builtin_amdgcn_s_barrier(); \
    __builtin_amdgcn_sched_barrier(0);
// end-step barrier: readers done (ds_reads drained); NO vm drain
#define ENDBAR() \
    asm volatile("s_waitcnt lgkmcnt(0)" ::: "memory"); \
    __builtin_amdgcn_sched_barrier(0); \
    __builtin_amdgcn_s_barrier(); \
    __builtin_amdgcn_sched_barrier(0);

    auto compute = [&](int sel) {
        const char* Bbase = (const char*)&Bbuf[0];
        const char* Abase = (const char*)&Abuf[0][0] + sel * 4096;
        short8 bfr[4];
        #pragma unroll
        for (int fn = 0; fn < 4; ++fn) {
            int r = (w << 6) + (fn << 4) + lj;
            bfr[fn] = *(const short8*)(Bbase + r * 64 + kx);
        }
        #pragma unroll
        for (int fm = 0; fm < 4; ++fm) {
            int rA = (fm << 4) + lj;
            short8 af = *(const short8*)(Abase + rA * 64 + kx);
            #pragma unroll
            for (int fn = 0; fn < 4; ++fn)
                acc[fm][fn] = __builtin_amdgcn_mfma_f32_16x16x32_bf16(af, bfr[fn], acc[fm][fn], 0, 0, 0);
        }
    };

    // ---- prologue: A(0),A(1) in regs; A(0) -> buf0 ----
    f32x4 aR0, aR1;
    LOADA(aR0, 0);
    LOADA(aR1, 1);
    WRITEA(0, aR0);                 // compiler waits the A(0) load
    // aR0 free for A(2)

    // ---- main loop: per step: STAGEB | WRITEA(A kt+1) | LOADA(A kt+2) |
    //      MIDBAR(vmcnt=1: A-load rides) | COMPUTE | ENDBAR (lgkm only) ----
    for (int kt2 = 0; kt2 < 30; kt2 += 2) {
        // kt even
        STAGEB(kt2)
        WRITEA(1, aR1);             // A(kt2+1) -> buf1 (auto-waits its load)
        LOADA(aR0, kt2 + 2);        // newest vm op
        MIDBAR(1)
        compute(0);
        ENDBAR()
        // kt odd
        STAGEB(kt2 + 1)
        WRITEA(0, aR0);             // A(kt2+2) -> buf0
        LOADA(aR1, kt2 + 3);
        MIDBAR(1)
        compute(1);
        ENDBAR()
    }
    // kt = 30
    STAGEB(30)
    WRITEA(1, aR1);                 // A(31)
    MIDBAR(0)
    compute(0);
    ENDBAR()
    // kt = 31
    STAGEB(31)
    MIDBAR(0)
    compute(1);

#undef LOADA
#undef WRITEA
#undef STAGEB
#undef MIDBAR
#undef ENDBAR

    // ---- epilogue: v = acc + dep + pa*wcv; tanh; *w_warp; reduce over h ----
    float dep4[4], wcv4[4], wwp4[4];
    #pragma unroll
    for (int fn = 0; fn < 4; ++fn) {
        int h = (w << 6) + (fn << 4) + lj;
        dep4[fn] = dp[b * TRG_ + h];
        wcv4[fn] = w_cv[h];
        wwp4[fn] = w_warp[h];
    }
    #pragma unroll
    for (int fm = 0; fm < 4; ++fm) {
        #pragma unroll
        for (int reg = 0; reg < 4; ++reg) {
            int row = (fm << 4) + (lg << 2) + reg;       // 0..63
            float pa = past_attn[m0 + row];
            float p = 0.f;
            #pragma unroll
            for (int fn = 0; fn < 4; ++fn) {
                float v = acc[fm][fn][reg] + dep4[fn] + pa * wcv4[fn];
                float e = __expf(2.f * v);                       // tanh = 1 - 2/(e^{2v}+1)
                float t = 1.f - 2.f * __builtin_amdgcn_rcpf(e + 1.f);
                p += t * wwp4[fn];
            }
            p += __shfl_xor(p, 1);
            p += __shfl_xor(p, 2);
            p += __shfl_xor(p, 4);
            p += __shfl_xor(p, 8);
            if (lj == 0) red[w][row] = p;
        }
    }
    __syncthreads();
    if (tid < 64) {
        float ee = 0.f;
        #pragma unroll
        for (int ww = 0; ww < 8; ++ww) ee += red[ww][tid];
        int msk = src_mask[m0 + tid];
        if (msk == 0) ee = -1e20f;
        out_ee[m0 + tid] = ee;
    }
}

// ---------------- softmax over S per batch row ----------------
__global__ void softmax_kernel(const float* __restrict__ ee, float* __restrict__ attn) {
    int b = blockIdx.x, tid = threadIdx.x;
    const float* row = ee + (size_t)b * S_;
    float v[8]; float mx = -3.0e38f;
    #pragma unroll
    for (int i = 0; i < 8; ++i) { v[i] = row[tid + (i << 8)]; mx = fmaxf(mx, v[i]); }
    #pragma unroll
    for (int off = 32; off > 0; off >>= 1) mx = fmaxf(mx, __shfl_xor(mx, off));
    __shared__ float sred[4];
    int w = tid >> 6, lane = tid & 63;
    if (lane == 0) sred[w] = mx;
    __syncthreads();
    mx = fmaxf(fmaxf(sred[0], sred[1]), fmaxf(sred[2], sred[3]));
    float sum = 0.f;
    #pragma unroll
    for (int i = 0; i < 8; ++i) { v[i] = __expf(v[i] - mx); sum += v[i]; }
    #pragma unroll
    for (int off = 32; off > 0; off >>= 1) sum += __shfl_xor(sum, off);
    __syncthreads();
    if (lane == 0) sred[w] = sum;
    __syncthreads();
    sum = sred[0] + sred[1] + sred[2] + sred[3];
    float inv = 1.f / sum;
    float* orow = attn + (size_t)b * S_;
    #pragma unroll
    for (int i = 0; i < 8; ++i) orow[tid + (i << 8)] = v[i] * inv;
}

// ---------------- context ----------------
__global__ void ctx_partial_kernel(const float* __restrict__ attn,
                                   const float* __restrict__ enhy,
                                   float* __restrict__ part) {
    int bx = blockIdx.x;
    int b = bx >> 5, sc = bx & 31;
    int tid = threadIdx.x;
    const float4* e4 = (const float4*)(enhy + ((size_t)b * S_ + sc * 64) * K_);
    const float* ar = attn + (size_t)b * S_ + sc * 64;
    float4 acc = {0.f, 0.f, 0.f, 0.f};
    #pragma unroll 8
    for (int s = 0; s < 64; ++s) {
        float a = ar[s];
        float4 ev = e4[(size_t)s * 256 + tid];
        acc.x += a * ev.x; acc.y += a * ev.y; acc.z += a * ev.z; acc.w += a * ev.w;
    }
    ((float4*)part)[(size_t)(sc * 64 + b) * 256 + tid] = acc;
}

__global__ void ctx_reduce_kernel(const float* __restrict__ part, float* __restrict__ outc) {
    int idx = blockIdx.x * 256 + threadIdx.x;
    int b = idx >> 10, d = idx & 1023;
    float s = 0.f;
    #pragma unroll
    for (int sc = 0; sc < 32; ++sc) s += part[(size_t)((sc << 6) + b) * 1024 + d];
    outc[idx] = s;
}

extern "C" void kernel_launch(void* const* d_in, const int* in_sizes, int n_in,
                              void* d_out, int out_size, void* d_ws, size_t ws_size,
                              hipStream_t stream) {
    (void)in_sizes; (void)n_in; (void)out_size; (void)ws_size;

    const float* dehy = (const float*)d_in[0];
    const float* enhy = (const float*)d_in[1];
    const float* past = (const float*)d_in[2];
    const int*   mask = (const int*)d_in[3];
    const float* Wen  = (const float*)d_in[4];
    const float* ben  = (const float*)d_in[5];
    const float* Wde  = (const float*)d_in[6];
    const float* wcv  = (const float*)d_in[7];
    const float* wwp  = (const float*)d_in[8];

    float* out      = (float*)d_out;
    float* out_c    = out;                      // 64*1024
    float* out_attn = out + 65536;              // 64*2048
    float* out_ee   = out + 65536 + 131072;     // 64*2048

    char* ws = (char*)d_ws;
    unsigned short* Wbf = (unsigned short*)ws;              // 1 MB
    float* dp   = (float*)(ws + (1 << 20));                 // 128 KB
    float* part = (float*)(ws + (1 << 20) + (1 << 17));     // 8 MB

    wen_convert_kernel<<<512, 256, 0, stream>>>(Wen, Wbf);
    deproj_kernel<<<128, 256, 0, stream>>>(dehy, Wde, ben, dp);
    score_kernel<<<2048, 512, 0, stream>>>(enhy, Wbf, dp, past, mask, wcv, wwp, out_ee);
    softmax_kernel<<<64, 256, 0, stream>>>(out_ee, out_attn);
    ctx_partial_kernel<<<2048, 256, 0, stream>>>(out_attn, enhy, part);
    ctx_reduce_kernel<<<256, 256, 0, stream>>>(part, out_c);
}